// Round 7
// baseline (183.768 us; speedup 1.0000x reference)
//
#include <hip/hip_runtime.h>
#include <hip/hip_bf16.h>
#include <stdint.h>

// TT linear 4096->4096, B=2048, ranks (1,16,16,16,1), modes 8^4.
// R15: barrier-domain split. 128x128 tile, BK=32, 256 thr (4 waves 2x2,
// per-wave 64x64 = 4x4 frags 16x16x32), grid 512 = 2 blocks/CU. Two
// independent 4-wave barrier groups per CU: one block's boundary drain
// overlaps the other block's MFMA (attacks the m114-style all-waves-
// in-barrier stall that R14's single 8-wave group couldn't hide).
// Triple-buffered LDS 3x16KB=48KB/block (2x48=96<=160), counted boundary
// {vmcnt(4) lgkmcnt(0); s_barrier}. BK=32 uses a FOLDED layout to keep
// the verified 128-B line + 8-chunk XOR swizzle: line u holds rows
// {2u,2u+1} (32 k each); logical chunk cl = p*4+kc (p=row parity,
// kc=k-chunk), phys = cl ^ (u&7). Per-16-lane-group chunk distribution
// = 8 values x 2 lanes, identical class to the measured-0-conflict R11
// pattern. SQ_LDS_BANK_CONFLICT is the go/no-go: >1M => revert to R14.
// XCD quadrant mapping: XCD owns 8bm x 8bn (bijective over 512).
// prep0/build_w = R1 verbatim (harness-verified).

typedef __bf16 bf16_t;
typedef __bf16 bf16x8 __attribute__((ext_vector_type(8)));
typedef __bf16 bf16x4 __attribute__((ext_vector_type(4)));
typedef float floatx4 __attribute__((ext_vector_type(4)));

#define BATCH_N 2048
#define KD 4096
#define ND 4096

__device__ static inline void load_lds16(const void* g, void* l) {
    __builtin_amdgcn_global_load_lds(
        (const __attribute__((address_space(1))) void*)g,
        (__attribute__((address_space(3))) void*)l, 16, 0, 0);
}

// ---- prep0: blocks [0,4096) cvt x fp32->bf16; blocks [4096,4160) build
//      P[n01][m01][r2]; blocks [4160,4224) build T[m23][n23][r2] --------
__global__ __launch_bounds__(256) void prep0(const float* __restrict__ x,
                                             const float* __restrict__ c0,
                                             const float* __restrict__ c1,
                                             const float* __restrict__ c2,
                                             const float* __restrict__ c3,
                                             bf16_t* __restrict__ xb,
                                             float* __restrict__ Pg,
                                             float* __restrict__ Tg) {
    const int t = threadIdx.x;
    const int b = blockIdx.x;

    if (b < 4096) {                     // ---- cvt_x ----
        int g = b * 256 + t;
        const float4* xv = (const float4*)x;
        float4 a = xv[g * 2];
        float4 c = xv[g * 2 + 1];
        bf16x8 o;
        o[0] = (bf16_t)a.x; o[1] = (bf16_t)a.y; o[2] = (bf16_t)a.z; o[3] = (bf16_t)a.w;
        o[4] = (bf16_t)c.x; o[5] = (bf16_t)c.y; o[6] = (bf16_t)c.z; o[7] = (bf16_t)c.w;
        ((bf16x8*)xb)[g] = o;
        return;
    }

    __shared__ float s0[128];
    __shared__ float s1[2048];

    if (b < 4160) {                     // ---- P[n01][m01][r2] ----
        const int n01 = b - 4096, n0 = n01 >> 3, n1 = n01 & 7;
        if (t < 128) s0[t] = c0[(t >> 4) * 128 + n0 * 16 + (t & 15)];   // [m0][r1]
        for (int i = t; i < 2048; i += 256) {                            // [r1][m1][r2]
            int r1 = i >> 7, m1 = (i >> 4) & 7, r2 = i & 15;
            s1[i] = c1[(r1 * 8 + m1) * 128 + n1 * 16 + r2];
        }
        __syncthreads();
#pragma unroll
        for (int j = 0; j < 4; ++j) {
            int o = j * 256 + t, m01 = o >> 4, r2 = o & 15;
            int m0 = m01 >> 3, m1 = m01 & 7;
            float s = 0.f;
#pragma unroll
            for (int r1 = 0; r1 < 16; ++r1)
                s += s0[m0 * 16 + r1] * s1[r1 * 128 + m1 * 16 + r2];
            Pg[n01 * 1024 + o] = s;
        }
        return;
    }

    {                                   // ---- T[m23][n23][r2] ----
        const int m23 = b - 4160, m2 = m23 >> 3, m3 = m23 & 7;
        if (t < 128) s0[t] = c3[((t >> 3) * 8 + m3) * 8 + (t & 7)];     // [r3][n3]
        for (int i = t; i < 2048; i += 256) {                            // [r2][n2][r3]
            int r2 = i >> 7, n2 = (i >> 4) & 7, r3 = i & 15;
            s1[i] = c2[(r2 * 8 + m2) * 128 + n2 * 16 + r3];
        }
        __syncthreads();
#pragma unroll
        for (int j = 0; j < 4; ++j) {
            int o = j * 256 + t, n23 = o >> 4, r2 = o & 15;
            int n2 = n23 >> 3, n3 = n23 & 7;
            float s = 0.f;
#pragma unroll
            for (int r3 = 0; r3 < 16; ++r3)
                s += s1[r2 * 128 + n2 * 16 + r3] * s0[r3 * 8 + n3];
            Tg[m23 * 1024 + o] = s;
        }
    }
}

// ---- build_w: 256 blocks = (q in [0,4)) x (n01 in [0,64)). (R1 verbatim)
__global__ __launch_bounds__(256) void build_w(const float* __restrict__ Pg,
                                               const float* __restrict__ Tg,
                                               bf16_t* __restrict__ W) {
    const int t = threadIdx.x;
    const int b = blockIdx.x;
    const int n01 = b & 63, q = b >> 6;
    const int cg = t & 15;
    const int mr = t >> 4;
    const float* Pb = Pg + n01 * 1024 + q * 256;   // Pb[ml*16 + r2], uniform

#pragma unroll 1
    for (int ms = 0; ms < 4; ++ms) {
        const int m23 = ms * 16 + mr;
        float Tr[4][16];
#pragma unroll
        for (int jj = 0; jj < 4; ++jj) {
            const float4* tp = (const float4*)(Tg + (m23 * 64 + cg * 4 + jj) * 16);
#pragma unroll
            for (int w = 0; w < 4; ++w) {
                float4 v = tp[w];
                Tr[jj][w * 4 + 0] = v.x;
                Tr[jj][w * 4 + 1] = v.y;
                Tr[jj][w * 4 + 2] = v.z;
                Tr[jj][w * 4 + 3] = v.w;
            }
        }
#pragma unroll 4
        for (int ml = 0; ml < 16; ++ml) {
            float a0 = 0.f, a1 = 0.f, a2 = 0.f, a3 = 0.f;
#pragma unroll
            for (int r2 = 0; r2 < 16; ++r2) {
                float p = Pb[ml * 16 + r2];     // wave-uniform -> SGPR
                a0 += p * Tr[0][r2];
                a1 += p * Tr[1][r2];
                a2 += p * Tr[2][r2];
                a3 += p * Tr[3][r2];
            }
            bf16x4 o;
            o[0] = (bf16_t)a0; o[1] = (bf16_t)a1; o[2] = (bf16_t)a2; o[3] = (bf16_t)a3;
            *(bf16x4*)(W + (size_t)((q * 16 + ml) * 64 + m23) * 4096 + n01 * 64 + cg * 4) = o;
        }
    }
}

// ---- BT GEMM R15: C[m,n] = sum_k A[m,k]*B[n,k] + bias[n] ---------------
// 128x128 tile, BK=32 folded LDS, 256 thr, grid 512 (2 blocks/CU).
__global__ __launch_bounds__(256, 3) void gemm_bt4(const bf16_t* __restrict__ A,
                                                   const bf16_t* __restrict__ B,
                                                   const float* __restrict__ bias,
                                                   float* __restrict__ C) {
    // per buf: A lines [0,4096) elems, B lines [4096,8192) elems (16 KB)
    __shared__ bf16_t smem[3][8192];
    const int t = threadIdx.x;
    const int bid = blockIdx.x;
    // Quadrant XCD mapping over 512 blocks: XCD x owns bm in [(x&1)*8,+8)
    // x bn in [(x>>1)*8,+8). 64 blocks/XCD, bijective.
    const int xcd = bid & 7, i = bid >> 3;        // i in [0,64)
    const int bm = (xcd & 1) * 8 + (i & 7);       // [0,16)
    const int bn = (xcd >> 1) * 8 + (i >> 3);     // [0,32)
    const int lane = t & 63, wave = t >> 6;
    const int wm = wave >> 1, wn = wave & 1;

    // ---- DMA source (folded layout, swizzle on the global side) ----
    // thread t, call c: LDS bytes [c*4096 + t*16, +16) = line u = c*32+(t>>3),
    // phys chunk cp = t&7. cl = cp ^ (u&7) ((c*32)&7==0); p = cl>>2, kc = cl&3.
    // content = row (c*64 + 2*(t>>3) + p), k-chunk kc.
    const int cl = (t & 7) ^ ((t >> 3) & 7);
    const int fp = cl >> 2, fkc = cl & 3;
    const bf16_t* Ag = A + (size_t)(bm * 128 + 2 * (t >> 3) + fp) * KD + fkc * 8;
    const bf16_t* Bg = B + (size_t)(bn * 128 + 2 * (t >> 3) + fp) * KD + fkc * 8;
    const int woff = wave * 512;                  // elems: wave's 1KB slice

    floatx4 acc[4][4];
    floatx4 zero = {0.f, 0.f, 0.f, 0.f};
#pragma unroll
    for (int i2 = 0; i2 < 4; ++i2)
#pragma unroll
        for (int j = 0; j < 4; ++j) acc[i2][j] = zero;

    // ---- ds_read addressing (folded): row r = base + im*16 + fr ->
    // line u = base/2 + im*8 + (fr>>1), chunk = ((fr&1)*4 + fc) ^ (fr>>1)
    const int fr = lane & 15;
    const int fc = lane >> 4;
    const int fr2 = fr >> 1;
    const int chOff = ((((fr & 1) << 2) | fc) ^ fr2) * 8;   // elems

    // ---- prologue: stage tiles 0 and 1 (4 calls each) ----
#pragma unroll
    for (int kt = 0; kt < 2; ++kt) {
        bf16_t* bb = &smem[kt][0];
        const size_t ko = (size_t)kt * 32;
#pragma unroll
        for (int c = 0; c < 2; ++c) {
            load_lds16(Ag + (size_t)c * 64 * KD + ko, bb + c * 2048 + woff);
            load_lds16(Bg + (size_t)c * 64 * KD + ko, bb + 4096 + c * 2048 + woff);
        }
    }
    asm volatile("s_waitcnt vmcnt(4)\n\ts_barrier" ::: "memory");

    int cur = 0;
#pragma unroll 1
    for (int kt = 0; kt < 128; ++kt) {
        // stage tile kt+2 into buf (cur+2)%3
        if (kt < 126) {
            int nb = cur + 2; if (nb >= 3) nb -= 3;
            bf16_t* bb = &smem[nb][0];
            const size_t ko = (size_t)(kt + 2) * 32;
#pragma unroll
            for (int c = 0; c < 2; ++c) {
                load_lds16(Ag + (size_t)c * 64 * KD + ko, bb + c * 2048 + woff);
                load_lds16(Bg + (size_t)c * 64 * KD + ko, bb + 4096 + c * 2048 + woff);
            }
        }

        const bf16_t* Ab = &smem[cur][0];
        const bf16_t* Bb = &smem[cur][4096];
        bf16x8 af[4], bf[4];
#pragma unroll
        for (int im = 0; im < 4; ++im)
            af[im] = *(const bf16x8*)(Ab + (wm * 32 + im * 8 + fr2) * 64 + chOff);
#pragma unroll
        for (int in = 0; in < 4; ++in)
            bf[in] = *(const bf16x8*)(Bb + (wn * 32 + in * 8 + fr2) * 64 + chOff);
        __builtin_amdgcn_s_setprio(1);
#pragma unroll
        for (int im = 0; im < 4; ++im)
#pragma unroll
            for (int in = 0; in < 4; ++in)
                acc[im][in] = __builtin_amdgcn_mfma_f32_16x16x32_bf16(
                    af[im], bf[in], acc[im][in], 0, 0, 0);
        __builtin_amdgcn_s_setprio(0);

        // Boundary: keep 4 loads (tile kt+2) in flight; drain lgkm so no
        // wave crosses with pending ds_reads of buf[cur] (recycled next
        // iter by DMA from other waves).
        if (kt < 126) {
            asm volatile("s_waitcnt vmcnt(4) lgkmcnt(0)\n\ts_barrier" ::: "memory");
        } else if (kt == 126) {
            asm volatile("s_waitcnt vmcnt(0) lgkmcnt(0)\n\ts_barrier" ::: "memory");
        }
        cur = (cur == 2) ? 0 : cur + 1;
    }

    // epilogue: D[m = (lane>>4)*4 + r][n = lane&15] per 16x16 frag
    const int rl = lane >> 4, cl2 = lane & 15;
    const size_t rbase = (size_t)bm * 128 + wm * 64;
    const int cbase = bn * 128 + wn * 64;
#pragma unroll
    for (int im = 0; im < 4; ++im) {
#pragma unroll
        for (int in = 0; in < 4; ++in) {
            int col = cbase + in * 16 + cl2;
            float bv = bias[col];
#pragma unroll
            for (int r = 0; r < 4; ++r) {
                size_t row = rbase + im * 16 + rl * 4 + r;
                C[row * ND + col] = acc[im][in][r] + bv;
            }
        }
    }
}

extern "C" void kernel_launch(void* const* d_in, const int* in_sizes, int n_in,
                              void* d_out, int out_size, void* d_ws, size_t ws_size,
                              hipStream_t stream) {
    const float* x  = (const float*)d_in[0];
    const float* c0 = (const float*)d_in[1];
    const float* c1 = (const float*)d_in[2];
    const float* c2 = (const float*)d_in[3];
    const float* c3 = (const float*)d_in[4];
    const float* bias = (const float*)d_in[5];
    float* out = (float*)d_out;

    char* ws = (char*)d_ws;
    bf16_t* Xb = (bf16_t*)ws;                 // 16 MiB
    bf16_t* W  = (bf16_t*)(ws + (16u << 20)); // 32 MiB

    // P/T factor tables (512 KB) live at the front of d_out: written by
    // prep0, read by build_w, fully overwritten by gemm_bt4 afterwards.
    float* Pg = (float*)d_out;                // 64*64*16 fp32 = 256 KB
    float* Tg = Pg + 64 * 1024;               // 64*64*16 fp32 = 256 KB

    prep0<<<4224, 256, 0, stream>>>(x, c0, c1, c2, c3, Xb, Pg, Tg);
    build_w<<<256, 256, 0, stream>>>(Pg, Tg, W);
    gemm_bt4<<<512, 256, 0, stream>>>(Xb, W, bias, out);
}

// Round 8
// 181.449 us; speedup vs baseline: 1.0128x; 1.0128x over previous
//
#include <hip/hip_runtime.h>
#include <hip/hip_bf16.h>
#include <stdint.h>

// TT linear 4096->4096, B=2048, ranks (1,16,16,16,1), modes 8^4.
// R16: LDS-read-ratio restructure. R14's counters show dur = LDS-pipe
// floor (1536cy) + MFMA floor (1241cy) per iter, serialized: 41+33us=74us
// measured. Fix lever: per-wave 64x128 output (4x8 frags) cuts ds_read
// per MFMA from 0.5 to 0.375 -> LDS floor 1152cy < MFMA 1241cy.
// Same 128x256 tile, BK=64, triple-buffered LDS (3x48KB=144KB), counted
// boundary {vmcnt(12) lgkmcnt(0); s_barrier} (12 loads per staged tile,
// kept in flight across the barrier), quadrant XCD mapping (R14's
// verified FETCH 139->65MB), R8 XOR-swizzle staging. Now 4 waves (2Mx2N),
// 256 thr, grid 256 = 1 block/CU = 1 wave/SIMD; 32 independent acc
// chains keep the MFMA pipe fed from a single wave.
// prep0/build_w = R1 verbatim (harness-verified).

typedef __bf16 bf16_t;
typedef __bf16 bf16x8 __attribute__((ext_vector_type(8)));
typedef __bf16 bf16x4 __attribute__((ext_vector_type(4)));
typedef float floatx4 __attribute__((ext_vector_type(4)));

#define BATCH_N 2048
#define KD 4096
#define ND 4096

__device__ static inline void load_lds16(const void* g, void* l) {
    __builtin_amdgcn_global_load_lds(
        (const __attribute__((address_space(1))) void*)g,
        (__attribute__((address_space(3))) void*)l, 16, 0, 0);
}

// ---- prep0: blocks [0,4096) cvt x fp32->bf16; blocks [4096,4160) build
//      P[n01][m01][r2]; blocks [4160,4224) build T[m23][n23][r2] --------
__global__ __launch_bounds__(256) void prep0(const float* __restrict__ x,
                                             const float* __restrict__ c0,
                                             const float* __restrict__ c1,
                                             const float* __restrict__ c2,
                                             const float* __restrict__ c3,
                                             bf16_t* __restrict__ xb,
                                             float* __restrict__ Pg,
                                             float* __restrict__ Tg) {
    const int t = threadIdx.x;
    const int b = blockIdx.x;

    if (b < 4096) {                     // ---- cvt_x ----
        int g = b * 256 + t;
        const float4* xv = (const float4*)x;
        float4 a = xv[g * 2];
        float4 c = xv[g * 2 + 1];
        bf16x8 o;
        o[0] = (bf16_t)a.x; o[1] = (bf16_t)a.y; o[2] = (bf16_t)a.z; o[3] = (bf16_t)a.w;
        o[4] = (bf16_t)c.x; o[5] = (bf16_t)c.y; o[6] = (bf16_t)c.z; o[7] = (bf16_t)c.w;
        ((bf16x8*)xb)[g] = o;
        return;
    }

    __shared__ float s0[128];
    __shared__ float s1[2048];

    if (b < 4160) {                     // ---- P[n01][m01][r2] ----
        const int n01 = b - 4096, n0 = n01 >> 3, n1 = n01 & 7;
        if (t < 128) s0[t] = c0[(t >> 4) * 128 + n0 * 16 + (t & 15)];   // [m0][r1]
        for (int i = t; i < 2048; i += 256) {                            // [r1][m1][r2]
            int r1 = i >> 7, m1 = (i >> 4) & 7, r2 = i & 15;
            s1[i] = c1[(r1 * 8 + m1) * 128 + n1 * 16 + r2];
        }
        __syncthreads();
#pragma unroll
        for (int j = 0; j < 4; ++j) {
            int o = j * 256 + t, m01 = o >> 4, r2 = o & 15;
            int m0 = m01 >> 3, m1 = m01 & 7;
            float s = 0.f;
#pragma unroll
            for (int r1 = 0; r1 < 16; ++r1)
                s += s0[m0 * 16 + r1] * s1[r1 * 128 + m1 * 16 + r2];
            Pg[n01 * 1024 + o] = s;
        }
        return;
    }

    {                                   // ---- T[m23][n23][r2] ----
        const int m23 = b - 4160, m2 = m23 >> 3, m3 = m23 & 7;
        if (t < 128) s0[t] = c3[((t >> 3) * 8 + m3) * 8 + (t & 7)];     // [r3][n3]
        for (int i = t; i < 2048; i += 256) {                            // [r2][n2][r3]
            int r2 = i >> 7, n2 = (i >> 4) & 7, r3 = i & 15;
            s1[i] = c2[(r2 * 8 + m2) * 128 + n2 * 16 + r3];
        }
        __syncthreads();
#pragma unroll
        for (int j = 0; j < 4; ++j) {
            int o = j * 256 + t, n23 = o >> 4, r2 = o & 15;
            int n2 = n23 >> 3, n3 = n23 & 7;
            float s = 0.f;
#pragma unroll
            for (int r3 = 0; r3 < 16; ++r3)
                s += s1[r2 * 128 + n2 * 16 + r3] * s0[r3 * 8 + n3];
            Tg[m23 * 1024 + o] = s;
        }
    }
}

// ---- build_w: 256 blocks = (q in [0,4)) x (n01 in [0,64)). (R1 verbatim)
__global__ __launch_bounds__(256) void build_w(const float* __restrict__ Pg,
                                               const float* __restrict__ Tg,
                                               bf16_t* __restrict__ W) {
    const int t = threadIdx.x;
    const int b = blockIdx.x;
    const int n01 = b & 63, q = b >> 6;
    const int cg = t & 15;
    const int mr = t >> 4;
    const float* Pb = Pg + n01 * 1024 + q * 256;   // Pb[ml*16 + r2], uniform

#pragma unroll 1
    for (int ms = 0; ms < 4; ++ms) {
        const int m23 = ms * 16 + mr;
        float Tr[4][16];
#pragma unroll
        for (int jj = 0; jj < 4; ++jj) {
            const float4* tp = (const float4*)(Tg + (m23 * 64 + cg * 4 + jj) * 16);
#pragma unroll
            for (int w = 0; w < 4; ++w) {
                float4 v = tp[w];
                Tr[jj][w * 4 + 0] = v.x;
                Tr[jj][w * 4 + 1] = v.y;
                Tr[jj][w * 4 + 2] = v.z;
                Tr[jj][w * 4 + 3] = v.w;
            }
        }
#pragma unroll 4
        for (int ml = 0; ml < 16; ++ml) {
            float a0 = 0.f, a1 = 0.f, a2 = 0.f, a3 = 0.f;
#pragma unroll
            for (int r2 = 0; r2 < 16; ++r2) {
                float p = Pb[ml * 16 + r2];     // wave-uniform -> SGPR
                a0 += p * Tr[0][r2];
                a1 += p * Tr[1][r2];
                a2 += p * Tr[2][r2];
                a3 += p * Tr[3][r2];
            }
            bf16x4 o;
            o[0] = (bf16_t)a0; o[1] = (bf16_t)a1; o[2] = (bf16_t)a2; o[3] = (bf16_t)a3;
            *(bf16x4*)(W + (size_t)((q * 16 + ml) * 64 + m23) * 4096 + n01 * 64 + cg * 4) = o;
        }
    }
}

// ---- BT GEMM R16: C[m,n] = sum_k A[m,k]*B[n,k] + bias[n] ---------------
// 128x256 tile, BK=64, 256 thr (4 waves 2Mx2N, per-wave 64x128 = 4x8
// frags 16x16x32), triple-buffered LDS, grid 256 (1 block/CU).
__global__ __launch_bounds__(256, 1) void gemm_bt5(const bf16_t* __restrict__ A,
                                                   const bf16_t* __restrict__ B,
                                                   const float* __restrict__ bias,
                                                   float* __restrict__ C) {
    __shared__ bf16_t smem[3][24576];   // per buf: A [0,8192), B [8192,24576)
    const int t = threadIdx.x;
    const int bid = blockIdx.x;
    // Quadrant XCD mapping (R14-verified): XCD x owns bm in [(x&1)*8,+8)
    // x bn in [(x>>1)*4,+4). Bijective over 256 blocks.
    const int xcd = bid & 7, gi = bid >> 3;       // gi in [0,32)
    const int bm = (xcd & 1) * 8 + (gi & 7);      // [0,16)
    const int bn = (xcd >> 1) * 4 + (gi >> 3);    // [0,16)
    const int lane = t & 63, wave = t >> 6;
    const int wm = wave >> 1, wn = wave & 1;

    // staging source (R8 swizzle, 256-thr variant): srow = t>>3 in [0,32),
    // chunk = (t&7)^(srow&7); call c covers rows [c*32,+32).
    const int srow = t >> 3;
    const int lc = (t & 7) ^ (srow & 7);
    const bf16_t* Ag = A + (size_t)(bm * 128 + srow) * KD + lc * 8;
    const bf16_t* Bg = B + (size_t)(bn * 256 + srow) * KD + lc * 8;
    const int woff = wave * 512;                  // elems: wave's 1KB slice

    floatx4 acc[4][8];
    floatx4 zero = {0.f, 0.f, 0.f, 0.f};
#pragma unroll
    for (int i2 = 0; i2 < 4; ++i2)
#pragma unroll
        for (int j = 0; j < 8; ++j) acc[i2][j] = zero;

    const int fr = lane & 15;
    const int fc = lane >> 4;

    // ---- prologue: stage tiles 0 and 1 (12 calls each) ----
#pragma unroll
    for (int kt = 0; kt < 2; ++kt) {
        bf16_t* bb = &smem[kt][0];
        const size_t ko = (size_t)kt * 64;
#pragma unroll
        for (int c = 0; c < 4; ++c)
            load_lds16(Ag + (size_t)c * 32 * KD + ko, bb + c * 2048 + woff);
#pragma unroll
        for (int c = 0; c < 8; ++c)
            load_lds16(Bg + (size_t)c * 32 * KD + ko, bb + 8192 + c * 2048 + woff);
    }
    asm volatile("s_waitcnt vmcnt(12)\n\ts_barrier" ::: "memory");

    int cur = 0;
#pragma unroll 1
    for (int kt = 0; kt < 64; ++kt) {
        // stage tile kt+2 into buf (cur+2)%3
        if (kt < 62) {
            int nb = cur + 2; if (nb >= 3) nb -= 3;
            bf16_t* bb = &smem[nb][0];
            const size_t ko = (size_t)(kt + 2) * 64;
#pragma unroll
            for (int c = 0; c < 4; ++c)
                load_lds16(Ag + (size_t)c * 32 * KD + ko, bb + c * 2048 + woff);
#pragma unroll
            for (int c = 0; c < 8; ++c)
                load_lds16(Bg + (size_t)c * 32 * KD + ko, bb + 8192 + c * 2048 + woff);
        }

        const bf16_t* Ab = &smem[cur][0];
        const bf16_t* Bb = &smem[cur][8192];
#pragma unroll
        for (int kk = 0; kk < 2; ++kk) {
            const int pA = (fc + kk * 4) ^ (fr & 7);
            bf16x8 af[4], bf[8];
#pragma unroll
            for (int im = 0; im < 4; ++im)
                af[im] = *(const bf16x8*)(Ab + (wm * 64 + im * 16 + fr) * 64 + pA * 8);
#pragma unroll
            for (int in = 0; in < 8; ++in)
                bf[in] = *(const bf16x8*)(Bb + (wn * 128 + in * 16 + fr) * 64 + pA * 8);
            __builtin_amdgcn_s_setprio(1);
#pragma unroll
            for (int im = 0; im < 4; ++im)
#pragma unroll
                for (int in = 0; in < 8; ++in)
                    acc[im][in] = __builtin_amdgcn_mfma_f32_16x16x32_bf16(
                        af[im], bf[in], acc[im][in], 0, 0, 0);
            __builtin_amdgcn_s_setprio(0);
        }

        // Boundary: keep 12 loads (tile kt+2) in flight; drain lgkm so no
        // wave crosses with pending ds_reads of buf[cur] (recycled next
        // iter by DMA from other waves).
        if (kt < 62) {
            asm volatile("s_waitcnt vmcnt(12) lgkmcnt(0)\n\ts_barrier" ::: "memory");
        } else if (kt == 62) {
            asm volatile("s_waitcnt vmcnt(0) lgkmcnt(0)\n\ts_barrier" ::: "memory");
        }
        cur = (cur == 2) ? 0 : cur + 1;
    }

    // epilogue: D[m = (lane>>4)*4 + r][n = lane&15] per 16x16 frag
    const int rl = lane >> 4, cl = lane & 15;
    const size_t rbase = (size_t)bm * 128 + wm * 64;
    const int cbase = bn * 256 + wn * 128;
#pragma unroll
    for (int im = 0; im < 4; ++im) {
#pragma unroll
        for (int in = 0; in < 8; ++in) {
            int col = cbase + in * 16 + cl;
            float bv = bias[col];
#pragma unroll
            for (int r = 0; r < 4; ++r) {
                size_t row = rbase + im * 16 + rl * 4 + r;
                C[row * ND + col] = acc[im][in][r] + bv;
            }
        }
    }
}

extern "C" void kernel_launch(void* const* d_in, const int* in_sizes, int n_in,
                              void* d_out, int out_size, void* d_ws, size_t ws_size,
                              hipStream_t stream) {
    const float* x  = (const float*)d_in[0];
    const float* c0 = (const float*)d_in[1];
    const float* c1 = (const float*)d_in[2];
    const float* c2 = (const float*)d_in[3];
    const float* c3 = (const float*)d_in[4];
    const float* bias = (const float*)d_in[5];
    float* out = (float*)d_out;

    char* ws = (char*)d_ws;
    bf16_t* Xb = (bf16_t*)ws;                 // 16 MiB
    bf16_t* W  = (bf16_t*)(ws + (16u << 20)); // 32 MiB

    // P/T factor tables (512 KB) live at the front of d_out: written by
    // prep0, read by build_w, fully overwritten by gemm_bt5 afterwards.
    float* Pg = (float*)d_out;                // 64*64*16 fp32 = 256 KB
    float* Tg = Pg + 64 * 1024;               // 64*64*16 fp32 = 256 KB

    prep0<<<4224, 256, 0, stream>>>(x, c0, c1, c2, c3, Xb, Pg, Tg);
    build_w<<<256, 256, 0, stream>>>(Pg, Tg, W);
    gemm_bt5<<<256, 256, 0, stream>>>(Xb, W, bias, out);
}

// Round 9
// 170.849 us; speedup vs baseline: 1.0756x; 1.0620x over previous
//
#include <hip/hip_runtime.h>
#include <hip/hip_bf16.h>
#include <stdint.h>

// TT linear 4096->4096, B=2048, ranks (1,16,16,16,1), modes 8^4.
// R17 = R14 (best measured: gemm 73.8us) + wave-parity kk-stagger.
// R14's counters: iter = 2770cy = MFMA floor (1241) + LDS-issue floor
// (1536) SERIALIZED — all 8 waves lockstep through {read burst, MFMA
// burst} each iteration, so the LDS pipe and matrix pipe alternate.
// Fix: even waves do kk0->kk1, odd waves kk1->kk0. At any instant half
// the waves read while half MFMA -> pipes co-run. No sync/addressing
// change; accumulation is commutative. Everything else identical to
// R14: 128x256 tile, BK=64, 512 thr (8 waves 2Mx4N, per-wave 64x64 =
// 4x4 frags 16x16x32), triple-buffered LDS (144KB), counted boundary
// {vmcnt(6) lgkmcnt(0); s_barrier}, quadrant XCD mapping (FETCH 65MB),
// R8 XOR-swizzle staging. prep0/build_w = R1 verbatim.

typedef __bf16 bf16_t;
typedef __bf16 bf16x8 __attribute__((ext_vector_type(8)));
typedef __bf16 bf16x4 __attribute__((ext_vector_type(4)));
typedef float floatx4 __attribute__((ext_vector_type(4)));

#define BATCH_N 2048
#define KD 4096
#define ND 4096

__device__ static inline void load_lds16(const void* g, void* l) {
    __builtin_amdgcn_global_load_lds(
        (const __attribute__((address_space(1))) void*)g,
        (__attribute__((address_space(3))) void*)l, 16, 0, 0);
}

// ---- prep0: blocks [0,4096) cvt x fp32->bf16; blocks [4096,4160) build
//      P[n01][m01][r2]; blocks [4160,4224) build T[m23][n23][r2] --------
__global__ __launch_bounds__(256) void prep0(const float* __restrict__ x,
                                             const float* __restrict__ c0,
                                             const float* __restrict__ c1,
                                             const float* __restrict__ c2,
                                             const float* __restrict__ c3,
                                             bf16_t* __restrict__ xb,
                                             float* __restrict__ Pg,
                                             float* __restrict__ Tg) {
    const int t = threadIdx.x;
    const int b = blockIdx.x;

    if (b < 4096) {                     // ---- cvt_x ----
        int g = b * 256 + t;
        const float4* xv = (const float4*)x;
        float4 a = xv[g * 2];
        float4 c = xv[g * 2 + 1];
        bf16x8 o;
        o[0] = (bf16_t)a.x; o[1] = (bf16_t)a.y; o[2] = (bf16_t)a.z; o[3] = (bf16_t)a.w;
        o[4] = (bf16_t)c.x; o[5] = (bf16_t)c.y; o[6] = (bf16_t)c.z; o[7] = (bf16_t)c.w;
        ((bf16x8*)xb)[g] = o;
        return;
    }

    __shared__ float s0[128];
    __shared__ float s1[2048];

    if (b < 4160) {                     // ---- P[n01][m01][r2] ----
        const int n01 = b - 4096, n0 = n01 >> 3, n1 = n01 & 7;
        if (t < 128) s0[t] = c0[(t >> 4) * 128 + n0 * 16 + (t & 15)];   // [m0][r1]
        for (int i = t; i < 2048; i += 256) {                            // [r1][m1][r2]
            int r1 = i >> 7, m1 = (i >> 4) & 7, r2 = i & 15;
            s1[i] = c1[(r1 * 8 + m1) * 128 + n1 * 16 + r2];
        }
        __syncthreads();
#pragma unroll
        for (int j = 0; j < 4; ++j) {
            int o = j * 256 + t, m01 = o >> 4, r2 = o & 15;
            int m0 = m01 >> 3, m1 = m01 & 7;
            float s = 0.f;
#pragma unroll
            for (int r1 = 0; r1 < 16; ++r1)
                s += s0[m0 * 16 + r1] * s1[r1 * 128 + m1 * 16 + r2];
            Pg[n01 * 1024 + o] = s;
        }
        return;
    }

    {                                   // ---- T[m23][n23][r2] ----
        const int m23 = b - 4160, m2 = m23 >> 3, m3 = m23 & 7;
        if (t < 128) s0[t] = c3[((t >> 3) * 8 + m3) * 8 + (t & 7)];     // [r3][n3]
        for (int i = t; i < 2048; i += 256) {                            // [r2][n2][r3]
            int r2 = i >> 7, n2 = (i >> 4) & 7, r3 = i & 15;
            s1[i] = c2[(r2 * 8 + m2) * 128 + n2 * 16 + r3];
        }
        __syncthreads();
#pragma unroll
        for (int j = 0; j < 4; ++j) {
            int o = j * 256 + t, n23 = o >> 4, r2 = o & 15;
            int n2 = n23 >> 3, n3 = n23 & 7;
            float s = 0.f;
#pragma unroll
            for (int r3 = 0; r3 < 16; ++r3)
                s += s1[r2 * 128 + n2 * 16 + r3] * s0[r3 * 8 + n3];
            Tg[m23 * 1024 + o] = s;
        }
    }
}

// ---- build_w: 256 blocks = (q in [0,4)) x (n01 in [0,64)). (R1 verbatim)
__global__ __launch_bounds__(256) void build_w(const float* __restrict__ Pg,
                                               const float* __restrict__ Tg,
                                               bf16_t* __restrict__ W) {
    const int t = threadIdx.x;
    const int b = blockIdx.x;
    const int n01 = b & 63, q = b >> 6;
    const int cg = t & 15;
    const int mr = t >> 4;
    const float* Pb = Pg + n01 * 1024 + q * 256;   // Pb[ml*16 + r2], uniform

#pragma unroll 1
    for (int ms = 0; ms < 4; ++ms) {
        const int m23 = ms * 16 + mr;
        float Tr[4][16];
#pragma unroll
        for (int jj = 0; jj < 4; ++jj) {
            const float4* tp = (const float4*)(Tg + (m23 * 64 + cg * 4 + jj) * 16);
#pragma unroll
            for (int w = 0; w < 4; ++w) {
                float4 v = tp[w];
                Tr[jj][w * 4 + 0] = v.x;
                Tr[jj][w * 4 + 1] = v.y;
                Tr[jj][w * 4 + 2] = v.z;
                Tr[jj][w * 4 + 3] = v.w;
            }
        }
#pragma unroll 4
        for (int ml = 0; ml < 16; ++ml) {
            float a0 = 0.f, a1 = 0.f, a2 = 0.f, a3 = 0.f;
#pragma unroll
            for (int r2 = 0; r2 < 16; ++r2) {
                float p = Pb[ml * 16 + r2];     // wave-uniform -> SGPR
                a0 += p * Tr[0][r2];
                a1 += p * Tr[1][r2];
                a2 += p * Tr[2][r2];
                a3 += p * Tr[3][r2];
            }
            bf16x4 o;
            o[0] = (bf16_t)a0; o[1] = (bf16_t)a1; o[2] = (bf16_t)a2; o[3] = (bf16_t)a3;
            *(bf16x4*)(W + (size_t)((q * 16 + ml) * 64 + m23) * 4096 + n01 * 64 + cg * 4) = o;
        }
    }
}

// ---- BT GEMM R17: C[m,n] = sum_k A[m,k]*B[n,k] + bias[n] ---------------
// Tile 128(M) x 256(N), BK=64, 512 threads (R14 body + kk-stagger).
__global__ __launch_bounds__(512, 2) void gemm_bt2(const bf16_t* __restrict__ A,
                                                   const bf16_t* __restrict__ B,
                                                   const float* __restrict__ bias,
                                                   float* __restrict__ C) {
    __shared__ bf16_t smem[3][24576];   // per buf: A [0,8192), B [8192,24576)
    const int t = threadIdx.x;
    const int bid = blockIdx.x;
    // Quadrant XCD mapping: XCD x owns bm in [(x&1)*8,+8) x bn in [(x>>1)*4,+4).
    const int xcd = bid & 7, i = bid >> 3;        // i in [0,32)
    const int bm = (xcd & 1) * 8 + (i & 7);       // [0,16)
    const int bn = (xcd >> 1) * 4 + (i >> 3);     // [0,16)
    const int lane = t & 63, wave = t >> 6;
    const int wm = wave >> 2, wn = wave & 3;
    const int kfirst = wave & 1;                  // stagger: odd waves kk1 first

    // staging source (R8 swizzle): srow = t>>3 in [0,64), chunk=(t&7)^(srow&7)
    const int srow = t >> 3;
    const int lc = (t & 7) ^ (srow & 7);
    const bf16_t* Ag = A + (size_t)(bm * 128 + srow) * KD + lc * 8;
    const bf16_t* Bg = B + (size_t)(bn * 256 + srow) * KD + lc * 8;
    const int woff = wave * 512;                  // LDS elems, wave-uniform

    floatx4 acc[4][4];
    floatx4 zero = {0.f, 0.f, 0.f, 0.f};
#pragma unroll
    for (int i2 = 0; i2 < 4; ++i2)
#pragma unroll
        for (int j = 0; j < 4; ++j) acc[i2][j] = zero;

    const int fr = lane & 15;
    const int fc = lane >> 4;

    // ---- prologue: stage tiles 0 and 1 ----
#pragma unroll
    for (int kt = 0; kt < 2; ++kt) {
        bf16_t* bb = &smem[kt][0];
        const size_t ko = (size_t)kt * 64;
#pragma unroll
        for (int c = 0; c < 2; ++c)
            load_lds16(Ag + (size_t)c * 64 * KD + ko, bb + c * 4096 + woff);
#pragma unroll
        for (int c = 0; c < 4; ++c)
            load_lds16(Bg + (size_t)c * 64 * KD + ko, bb + 8192 + c * 4096 + woff);
    }
    asm volatile("s_waitcnt vmcnt(6)\n\ts_barrier" ::: "memory");

    int cur = 0;
#pragma unroll 1
    for (int kt = 0; kt < 64; ++kt) {
        // stage tile kt+2 into buf (cur+2)%3
        if (kt < 62) {
            int nb = cur + 2; if (nb >= 3) nb -= 3;
            bf16_t* bb = &smem[nb][0];
            const size_t ko = (size_t)(kt + 2) * 64;
#pragma unroll
            for (int c = 0; c < 2; ++c)
                load_lds16(Ag + (size_t)c * 64 * KD + ko, bb + c * 4096 + woff);
#pragma unroll
            for (int c = 0; c < 4; ++c)
                load_lds16(Bg + (size_t)c * 64 * KD + ko, bb + 8192 + c * 4096 + woff);
        }

        const bf16_t* Ab = &smem[cur][0];
        const bf16_t* Bb = &smem[cur][8192];
#pragma unroll
        for (int s = 0; s < 2; ++s) {
            const int kk = kfirst ^ s;            // wave-parity stagger
            const int pA = (fc + kk * 4) ^ (fr & 7);
            bf16x8 af[4], bf[4];
#pragma unroll
            for (int im = 0; im < 4; ++im)
                af[im] = *(const bf16x8*)(Ab + (wm * 64 + im * 16 + fr) * 64 + pA * 8);
#pragma unroll
            for (int in = 0; in < 4; ++in)
                bf[in] = *(const bf16x8*)(Bb + (wn * 64 + in * 16 + fr) * 64 + pA * 8);
            __builtin_amdgcn_s_setprio(1);
#pragma unroll
            for (int im = 0; im < 4; ++im)
#pragma unroll
                for (int in = 0; in < 4; ++in)
                    acc[im][in] = __builtin_amdgcn_mfma_f32_16x16x32_bf16(
                        af[im], bf[in], acc[im][in], 0, 0, 0);
            __builtin_amdgcn_s_setprio(0);
        }

        // Boundary: keep 6 loads (tile kt+2) in flight; drain lgkm so no
        // wave crosses with pending ds_reads of buf[cur] (recycled next
        // iter by DMA from other waves).
        if (kt < 62) {
            asm volatile("s_waitcnt vmcnt(6) lgkmcnt(0)\n\ts_barrier" ::: "memory");
        } else if (kt == 62) {
            asm volatile("s_waitcnt vmcnt(0) lgkmcnt(0)\n\ts_barrier" ::: "memory");
        }
        cur = (cur == 2) ? 0 : cur + 1;
    }

    // epilogue: D[m = (lane>>4)*4 + r][n = lane&15] per 16x16 frag
    const int rl = lane >> 4, cl = lane & 15;
    const size_t rbase = (size_t)bm * 128 + wm * 64;
    const int cbase = bn * 256 + wn * 64;
#pragma unroll
    for (int im = 0; im < 4; ++im) {
#pragma unroll
        for (int in = 0; in < 4; ++in) {
            int col = cbase + in * 16 + cl;
            float bv = bias[col];
#pragma unroll
            for (int r = 0; r < 4; ++r) {
                size_t row = rbase + im * 16 + rl * 4 + r;
                C[row * ND + col] = acc[im][in][r] + bv;
            }
        }
    }
}

extern "C" void kernel_launch(void* const* d_in, const int* in_sizes, int n_in,
                              void* d_out, int out_size, void* d_ws, size_t ws_size,
                              hipStream_t stream) {
    const float* x  = (const float*)d_in[0];
    const float* c0 = (const float*)d_in[1];
    const float* c1 = (const float*)d_in[2];
    const float* c2 = (const float*)d_in[3];
    const float* c3 = (const float*)d_in[4];
    const float* bias = (const float*)d_in[5];
    float* out = (float*)d_out;

    char* ws = (char*)d_ws;
    bf16_t* Xb = (bf16_t*)ws;                 // 16 MiB
    bf16_t* W  = (bf16_t*)(ws + (16u << 20)); // 32 MiB

    // P/T factor tables (512 KB) live at the front of d_out: written by
    // prep0, read by build_w, fully overwritten by gemm_bt2 afterwards.
    float* Pg = (float*)d_out;                // 64*64*16 fp32 = 256 KB
    float* Tg = Pg + 64 * 1024;               // 64*64*16 fp32 = 256 KB

    prep0<<<4224, 256, 0, stream>>>(x, c0, c1, c2, c3, Xb, Pg, Tg);
    build_w<<<256, 256, 0, stream>>>(Pg, Tg, W);
    gemm_bt2<<<256, 512, 0, stream>>>(Xb, W, bias, out);
}